// Round 6
// baseline (1265.786 us; speedup 1.0000x reference)
//
#include <hip/hip_runtime.h>
#include <math.h>

static constexpr int Zc  = 64;
static constexpr int Xc  = 32;
static constexpr int THc = 128;
static constexpr int OHc = 64;
static constexpr int Bc  = 4096;
static constexpr int Tc  = 256;

__device__ __forceinline__ float sigf(float x) {
  float e = __expf(-x);
  return __builtin_amdgcn_rcpf(1.0f + e);
}
__device__ __forceinline__ float tanh_fast(float x) {
  float xc = fminf(fmaxf(x, -15.0f), 15.0f);
  float e  = __expf(-2.0f * xc);
  return (1.0f - e) * __builtin_amdgcn_rcpf(1.0f + e);
}
__device__ __forceinline__ float dot4(float4 w, float4 v) {
  return fmaf(w.x, v.x, fmaf(w.y, v.y, fmaf(w.z, v.z, w.w * v.w)));
}

// All weight storage is NAMED float4 locals (w0..w19) — no arrays, so SROA
// keeps them in VGPRs (arrays > PromoteAlloca limit go to scratch: R0-R2/R4
// evidence). Indexing is 100% compile-time.
#define LD16(A,B,C,D, SP) do { const float4* _p = (const float4*)(SP); \
    A = _p[0]; B = _p[1]; C = _p[2]; D = _p[3]; } while (0)
#define LD32(A,B,C,D,E,F,G,H, SP) do { LD16(A,B,C,D, SP); \
    LD16(E,F,G,H, ((const float*)(SP)) + 16); } while (0)

#define DOT16(A,B,C,D, XP) \
  (dot4(A, ((const float4*)(XP))[0]) + dot4(B, ((const float4*)(XP))[1]) + \
   dot4(C, ((const float4*)(XP))[2]) + dot4(D, ((const float4*)(XP))[3]))
#define DOT32(A,B,C,D,E,F,G,H, XP) \
  (DOT16(A,B,C,D, XP) + DOT16(E,F,G,H, ((const float*)(XP)) + 16))
#define DOT64(A,B,C,D,E,F,G,H,I,J,K,L,M,N,O,P, XP) \
  (DOT32(A,B,C,D,E,F,G,H, XP) + DOT32(I,J,K,L,M,N,O,P, ((const float*)(XP)) + 32))

// Serial recurrence, 1 block x 1024 threads (16 waves), 3 barriers/step.
// Wave roles:
//   0-7  : P1 GRU (8 lanes per output j, xor8/16/32 reduce)  [48 floats]
//          P2 trans half-rows gzh (wv<4) / pzh (wv>=4)        [+32 floats]
//   8-9  : P1 obs hidden (olh / osh, full rows)               [64 floats]
//   10   : P2 z_lin (W_zloc full rows)                        [64 floats]
//   11   : P2 obs final (olx lanes 0-31 / osx lanes 32-63)    [64 floats]
//   12-15: P3 gate+pm quarter-rows (xor16/32 reduce)          [64 floats]
// __launch_bounds__(1024) with NO second arg: 16 waves/CU -> 4 waves/SIMD ->
// 128-VGPR hardware budget; max role footprint ~110 VGPR fits. R3's (1024,4)
// capped allocation at 64 VGPR (counter evidence) and forced spills.
__global__ __launch_bounds__(1024) void chain_kernel(
    const float* __restrict__ z0, const float* __restrict__ h0,
    const float* __restrict__ W_ih, const float* __restrict__ W_hh,
    const float* __restrict__ b_ih, const float* __restrict__ b_hh,
    const float* __restrict__ W_gzh, const float* __restrict__ b_gzh,
    const float* __restrict__ W_ghz, const float* __restrict__ b_ghz,
    const float* __restrict__ W_pzh, const float* __restrict__ b_pzh,
    const float* __restrict__ W_phz, const float* __restrict__ b_phz,
    const float* __restrict__ W_zloc, const float* __restrict__ b_zloc,
    const float* __restrict__ W_olh, const float* __restrict__ b_olh,
    const float* __restrict__ W_olx, const float* __restrict__ b_olx,
    const float* __restrict__ W_osh, const float* __restrict__ b_osh,
    const float* __restrict__ W_osx, const float* __restrict__ b_osx,
    float* __restrict__ out) {
  const int tid  = threadIdx.x;
  const int lane = tid & 63;
  const int wv   = tid >> 6;   // 0..15

  __shared__ __align__(16) float zbuf[64];
  __shared__ __align__(16) float hA[64];
  __shared__ __align__(16) float hB[64];
  __shared__ __align__(16) float abuf[128];
  __shared__ __align__(16) float cbuf[128];
  __shared__ __align__(16) float zlinbuf[64];
  __shared__ __align__(16) float olbuf[64];
  __shared__ __align__(16) float osbuf[64];

  float4 w0{},w1{},w2{},w3{},w4{},w5{},w6{},w7{},w8{},w9{},
         w10{},w11{},w12{},w13{},w14{},w15{},w16{},w17{},w18{},w19{};
  float bA = 0.f, bB = 0.f, bC = 0.f, bD = 0.f, b2 = 0.f;

  // ---------------- weight staging ----------------
  if (wv < 8) {
    // GRU: output j, 16-col chunk q of concat [z|h] (q<4: W_ih, q>=4: W_hh)
    const int j = (wv << 3) + (lane & 7);
    const int q = lane >> 3;
    const float* Ws = (q < 4) ? W_ih : W_hh;
    const int c = (q & 3) * 16;
    LD16(w0, w1, w2, w3,  Ws + (j) * 64 + c);        // r row chunk
    LD16(w4, w5, w6, w7,  Ws + (64 + j) * 64 + c);   // u row chunk
    LD16(w8, w9, w10, w11, Ws + (128 + j) * 64 + c); // n row chunk
    bA = b_ih[j] + b_hh[j];
    bB = b_ih[64 + j] + b_hh[64 + j];
    bC = b_ih[128 + j];
    bD = b_hh[128 + j];
    // P2 half-row
    const int row  = ((wv & 3) << 5) + (lane & 31);
    const int half = lane >> 5;
    const float* Wp = (wv < 4) ? W_gzh : W_pzh;
    LD32(w12, w13, w14, w15, w16, w17, w18, w19, Wp + row * 64 + half * 32);
    b2 = (wv < 4) ? b_gzh[row] : b_pzh[row];
  } else if (wv < 10) {
    const float* Ws = (wv == 8) ? W_olh : W_osh;
    LD32(w0, w1, w2, w3, w4, w5, w6, w7,        Ws + lane * 64);
    LD32(w8, w9, w10, w11, w12, w13, w14, w15,  Ws + lane * 64 + 32);
    b2 = (wv == 8) ? b_olh[lane] : b_osh[lane];
  } else if (wv == 10) {
    LD32(w0, w1, w2, w3, w4, w5, w6, w7,        W_zloc + lane * 64);
    LD32(w8, w9, w10, w11, w12, w13, w14, w15,  W_zloc + lane * 64 + 32);
    b2 = b_zloc[lane];
  } else if (wv == 11) {
    const int r = lane & 31;
    const float* Ws = (lane < 32) ? W_olx : W_osx;
    LD32(w0, w1, w2, w3, w4, w5, w6, w7,        Ws + r * 64);
    LD32(w8, w9, w10, w11, w12, w13, w14, w15,  Ws + r * 64 + 32);
    b2 = (lane < 32) ? b_olx[r] : b_osx[r];
  } else {
    // P3: j-output, 32-col quarter q of TH=128
    const int j = ((wv & 3) << 4) + (lane & 15);
    const int q = lane >> 4;
    LD32(w0, w1, w2, w3, w4, w5, w6, w7,        W_ghz + j * 128 + q * 32);
    LD32(w8, w9, w10, w11, w12, w13, w14, w15,  W_phz + j * 128 + q * 32);
    bA = b_ghz[j];
    bB = b_phz[j];
  }

  if (tid < 64) { zbuf[tid] = z0[tid]; hA[tid] = h0[tid]; }
  __syncthreads();

  for (int t = 0; t <= Tc; ++t) {
    const bool step = (t < Tc);
    const bool obs  = (t >= 1);
    float* hold = (t & 1) ? hB : hA;
    float* hnew = (t & 1) ? hA : hB;

    // ---- P1: GRU (waves 0-7) || obs hidden of step t-1 (waves 8-9) ----
    if (step && wv < 8) {
      const int j = (wv << 3) + (lane & 7);
      const int q = lane >> 3;
      const float* x = ((q < 4) ? zbuf : hold) + (q & 3) * 16;
      float pr = DOT16(w0, w1, w2, w3, x);
      float pu = DOT16(w4, w5, w6, w7, x);
      float pn = DOT16(w8, w9, w10, w11, x);
      pr += __shfl_xor(pr, 8, 64);  pr += __shfl_xor(pr, 16, 64); pr += __shfl_xor(pr, 32, 64);
      pu += __shfl_xor(pu, 8, 64);  pu += __shfl_xor(pu, 16, 64); pu += __shfl_xor(pu, 32, 64);
      pn += __shfl_xor(pn, 8, 64);  pn += __shfl_xor(pn, 16, 64);
      float pno = __shfl_xor(pn, 32, 64);
      float i_n = ((q < 4) ? pn : pno) + bC;
      float h_n = ((q < 4) ? pno : pn) + bD;
      float r  = sigf(pr + bA);
      float u  = sigf(pu + bB);
      float nn = tanh_fast(i_n + r * h_n);
      float hv = (1.f - u) * nn + u * hold[j];
      if (q == 0) hnew[j] = hv;
    }
    if (obs && (wv == 8 || wv == 9)) {
      float acc = DOT64(w0, w1, w2, w3, w4, w5, w6, w7,
                        w8, w9, w10, w11, w12, w13, w14, w15, zbuf) + b2;
      acc = fmaxf(acc, 0.f);
      if (wv == 8) olbuf[lane] = acc; else osbuf[lane] = acc;
    }
    __syncthreads();

    // ---- P2: trans hiddens (waves 0-7) + z_lin (10) || obs final (11) ----
    if (step && wv < 8) {
      const int row  = ((wv & 3) << 5) + (lane & 31);
      const int half = lane >> 5;
      float s = DOT32(w12, w13, w14, w15, w16, w17, w18, w19, hnew + half * 32);
      s += __shfl_xor(s, 32, 64);
      if (lane < 32) {
        float v = fmaxf(s + b2, 0.f);
        if (wv < 4) abuf[row] = v; else cbuf[row] = v;
      }
    }
    if (step && wv == 10) {
      zlinbuf[lane] = DOT64(w0, w1, w2, w3, w4, w5, w6, w7,
                            w8, w9, w10, w11, w12, w13, w14, w15, hnew) + b2;
    }
    if (obs && wv == 11) {
      const float* x = (lane < 32) ? olbuf : osbuf;
      float acc = DOT64(w0, w1, w2, w3, w4, w5, w6, w7,
                        w8, w9, w10, w11, w12, w13, w14, w15, x) + b2;
      out[(size_t)(t - 1) * 64 + lane] = fmaxf(acc, 0.f);
    }
    __syncthreads();

    // ---- P3: gate + pm + z combine (waves 12-15) ----
    if (step && wv >= 12) {
      const int j = ((wv & 3) << 4) + (lane & 15);
      const int q = lane >> 4;
      float sg = DOT32(w0, w1, w2, w3, w4, w5, w6, w7, abuf + q * 32);
      float sp = DOT32(w8, w9, w10, w11, w12, w13, w14, w15, cbuf + q * 32);
      sg += __shfl_xor(sg, 16, 64); sg += __shfl_xor(sg, 32, 64);
      sp += __shfl_xor(sp, 16, 64); sp += __shfl_xor(sp, 32, 64);
      if (q == 0) {
        float g = sigf(sg + bA);
        zbuf[j] = (1.f - g) * zlinbuf[j] + g * (sp + bB);
      }
    }
    __syncthreads();
  }
}

// out[n] = out[n mod 16384] for n >= 16384; 16384 = T*2X is a power of two.
__global__ __launch_bounds__(256) void bcast_kernel(float* __restrict__ out) {
  const size_t total4 = (size_t)Bc * Tc * (2 * Xc) / 4;
  const size_t src4   = (size_t)Tc * (2 * Xc) / 4;
  const float4* s = (const float4*)out;
  float4* o = (float4*)out;
  size_t stride = (size_t)gridDim.x * blockDim.x;
  for (size_t i = (size_t)blockIdx.x * blockDim.x + threadIdx.x + src4;
       i < total4; i += stride) {
    o[i] = s[i & (src4 - 1)];
  }
}

extern "C" void kernel_launch(void* const* d_in, const int* in_sizes, int n_in,
                              void* d_out, int out_size, void* d_ws, size_t ws_size,
                              hipStream_t stream) {
  (void)in_sizes; (void)n_in; (void)d_ws; (void)ws_size; (void)out_size;
  const float* z0     = (const float*)d_in[1];
  const float* h0     = (const float*)d_in[2];
  const float* W_ih   = (const float*)d_in[3];
  const float* W_hh   = (const float*)d_in[4];
  const float* b_ih   = (const float*)d_in[5];
  const float* b_hh   = (const float*)d_in[6];
  const float* W_gzh  = (const float*)d_in[7];
  const float* b_gzh  = (const float*)d_in[8];
  const float* W_ghz  = (const float*)d_in[9];
  const float* b_ghz  = (const float*)d_in[10];
  const float* W_pzh  = (const float*)d_in[11];
  const float* b_pzh  = (const float*)d_in[12];
  const float* W_phz  = (const float*)d_in[13];
  const float* b_phz  = (const float*)d_in[14];
  const float* W_zloc = (const float*)d_in[15];
  const float* b_zloc = (const float*)d_in[16];
  const float* W_olh  = (const float*)d_in[19];
  const float* b_olh  = (const float*)d_in[20];
  const float* W_olx  = (const float*)d_in[21];
  const float* b_olx  = (const float*)d_in[22];
  const float* W_osh  = (const float*)d_in[23];
  const float* b_osh  = (const float*)d_in[24];
  const float* W_osx  = (const float*)d_in[25];
  const float* b_osx  = (const float*)d_in[26];
  float* out = (float*)d_out;

  chain_kernel<<<1, 1024, 0, stream>>>(
      z0, h0, W_ih, W_hh, b_ih, b_hh,
      W_gzh, b_gzh, W_ghz, b_ghz, W_pzh, b_pzh, W_phz, b_phz,
      W_zloc, b_zloc, W_olh, b_olh, W_olx, b_olx,
      W_osh, b_osh, W_osx, b_osx, out);

  bcast_kernel<<<2048, 256, 0, stream>>>(out);
}

// Round 7
// 439.412 us; speedup vs baseline: 2.8806x; 2.8806x over previous
//
#include <hip/hip_runtime.h>
#include <math.h>

static constexpr int Zc  = 64;
static constexpr int Xc  = 32;
static constexpr int Bc  = 4096;
static constexpr int Tc  = 256;

__device__ __forceinline__ float sigf(float x) {
  float e = __expf(-x);
  return __builtin_amdgcn_rcpf(1.0f + e);
}
__device__ __forceinline__ float tanh_fast(float x) {
  float xc = fminf(fmaxf(x, -15.0f), 15.0f);
  float e  = __expf(-2.0f * xc);
  return (1.0f - e) * __builtin_amdgcn_rcpf(1.0f + e);
}
__device__ __forceinline__ float dot4(float4 w, float4 v) {
  return fmaf(w.x, v.x, fmaf(w.y, v.y, fmaf(w.z, v.z, w.w * v.w)));
}
__device__ __forceinline__ float4 ld4(const float* p) { return *(const float4*)p; }

// Serial recurrence, 1 block x 512 threads (8 waves), 3 barriers/step.
// Per-thread PERMANENT register state = 24 named float4 (96 floats):
//   g0-g11 : GRU chunks (r,u,n gates; 16-fl K-chunk c of [z|h] concat)
//   pw0-7  : gzh/pzh half-row (P2)
//   q0-q3  : ghz eighth-row (P3)
// LDS holds phz (32KB) + zloc (16KB) in k-interleaved conflict-free layout,
// plus state buffers. Obs head runs in a separate parallel kernel.
__global__ __launch_bounds__(512) void chain_kernel(
    const float* __restrict__ z0, const float* __restrict__ h0,
    const float* __restrict__ W_ih, const float* __restrict__ W_hh,
    const float* __restrict__ b_ih, const float* __restrict__ b_hh,
    const float* __restrict__ W_gzh, const float* __restrict__ b_gzh,
    const float* __restrict__ W_ghz, const float* __restrict__ b_ghz,
    const float* __restrict__ W_pzh, const float* __restrict__ b_pzh,
    const float* __restrict__ W_phz, const float* __restrict__ b_phz,
    const float* __restrict__ W_zloc, const float* __restrict__ b_zloc,
    float* __restrict__ zout) {
  const int tid  = threadIdx.x;
  const int lane = tid & 63;
  const int j    = tid >> 3;        // 0..63  (P1 + P3 output index)
  const int c    = tid & 7;         // 0..7   (K-chunk / eighth index)
  const int o    = tid >> 1;        // 0..255 (P2 output index)
  const int hf   = tid & 1;         // P2 K-half
  const int jh   = tid >> 6;        // wave index (= j>>3)

  __shared__ __align__(16) float zbuf[64];
  __shared__ __align__(16) float hA[64];
  __shared__ __align__(16) float hB[64];
  __shared__ __align__(16) float abuf[128];
  __shared__ __align__(16) float cbuf[128];
  __shared__ __align__(16) float lds_phz[8192];  // [jh][k][lane] f4-interleaved
  __shared__ __align__(16) float lds_zl [4096];  // [jh][k][jl*4+c] f4-interleaved

  float4* zbuf4 = (float4*)zbuf;
  float4* abuf4 = (float4*)abuf;
  float4* cbuf4 = (float4*)cbuf;
  float4* phz4  = (float4*)lds_phz;
  float4* zl4   = (float4*)lds_zl;

  // ---------------- staging ----------------
  // GRU chunks: rows j, 64+j, 128+j of W_ih (c<4) or W_hh (c>=4), cols cc..cc+16
  const float* Wsrc = (c < 4) ? W_ih : W_hh;
  const int cc = (c & 3) * 16;
  float4 g0  = ld4(Wsrc + (j)       * 64 + cc +  0);
  float4 g1  = ld4(Wsrc + (j)       * 64 + cc +  4);
  float4 g2  = ld4(Wsrc + (j)       * 64 + cc +  8);
  float4 g3  = ld4(Wsrc + (j)       * 64 + cc + 12);
  float4 g4  = ld4(Wsrc + (64 + j)  * 64 + cc +  0);
  float4 g5  = ld4(Wsrc + (64 + j)  * 64 + cc +  4);
  float4 g6  = ld4(Wsrc + (64 + j)  * 64 + cc +  8);
  float4 g7  = ld4(Wsrc + (64 + j)  * 64 + cc + 12);
  float4 g8  = ld4(Wsrc + (128 + j) * 64 + cc +  0);
  float4 g9  = ld4(Wsrc + (128 + j) * 64 + cc +  4);
  float4 g10 = ld4(Wsrc + (128 + j) * 64 + cc +  8);
  float4 g11 = ld4(Wsrc + (128 + j) * 64 + cc + 12);
  const float br  = b_ih[j] + b_hh[j];
  const float bu  = b_ih[64 + j] + b_hh[64 + j];
  const float bin = b_ih[128 + j];
  const float bhn = b_hh[128 + j];

  // P2 half-row (gzh for o<128, pzh for o>=128)
  const float* Wp2 = (o < 128) ? (W_gzh + o * 64) : (W_pzh + (o - 128) * 64);
  const float* Wp2h = Wp2 + hf * 32;
  float4 pw0 = ld4(Wp2h +  0), pw1 = ld4(Wp2h +  4);
  float4 pw2 = ld4(Wp2h +  8), pw3 = ld4(Wp2h + 12);
  float4 pw4 = ld4(Wp2h + 16), pw5 = ld4(Wp2h + 20);
  float4 pw6 = ld4(Wp2h + 24), pw7 = ld4(Wp2h + 28);
  const float b2 = (o < 128) ? b_gzh[o] : b_pzh[o - 128];

  // P3 ghz eighth-row
  const float* Wq = W_ghz + j * 128 + c * 16;
  float4 q0 = ld4(Wq + 0), q1 = ld4(Wq + 4), q2 = ld4(Wq + 8), q3 = ld4(Wq + 12);
  const float bg = b_ghz[j];
  const float bp = b_phz[j];
  const float bz = b_zloc[j];

  // LDS phz, k-interleaved: chunk k of thread (j,c) -> phz4[jh*256 + k*64 + lane]
#pragma unroll
  for (int k = 0; k < 4; ++k)
    phz4[jh * 256 + k * 64 + lane] = ld4(W_phz + j * 128 + c * 16 + k * 4);
  // LDS zloc (threads c<4): chunk k -> zl4[jh*128 + k*32 + (j&7)*4 + c]
  if (c < 4) {
#pragma unroll
    for (int k = 0; k < 4; ++k)
      zl4[jh * 128 + k * 32 + (j & 7) * 4 + c] = ld4(W_zloc + j * 64 + c * 16 + k * 4);
  }

  if (tid < 64) { zbuf[tid] = z0[tid]; hA[tid] = h0[tid]; }
  __syncthreads();

  for (int t = 0; t < Tc; ++t) {
    float* hold = (t & 1) ? hB : hA;
    float* hnew = (t & 1) ? hA : hB;
    float4* hold4 = (float4*)hold;
    float4* hnew4 = (float4*)hnew;

    // ---- P1: GRU ----
    {
      const float4* x4 = ((c < 4) ? zbuf4 : hold4) + (c & 3) * 4;
      float pr = dot4(g0, x4[0]) + dot4(g1, x4[1]) + dot4(g2, x4[2]) + dot4(g3, x4[3]);
      float pu = dot4(g4, x4[0]) + dot4(g5, x4[1]) + dot4(g6, x4[2]) + dot4(g7, x4[3]);
      float pn = dot4(g8, x4[0]) + dot4(g9, x4[1]) + dot4(g10, x4[2]) + dot4(g11, x4[3]);
      pr += __shfl_xor(pr, 1, 64); pr += __shfl_xor(pr, 2, 64); pr += __shfl_xor(pr, 4, 64);
      pu += __shfl_xor(pu, 1, 64); pu += __shfl_xor(pu, 2, 64); pu += __shfl_xor(pu, 4, 64);
      pn += __shfl_xor(pn, 1, 64); pn += __shfl_xor(pn, 2, 64);
      float pno = __shfl_xor(pn, 4, 64);
      float i_n = ((c < 4) ? pn : pno) + bin;
      float h_n = ((c < 4) ? pno : pn) + bhn;
      float r  = sigf(pr + br);
      float u  = sigf(pu + bu);
      float nn = tanh_fast(i_n + r * h_n);
      float hv = (1.f - u) * nn + u * hold[j];
      if (c == 0) hnew[j] = hv;
    }
    __syncthreads();

    // ---- P2: trans hiddens (relu(gzh.h), relu(pzh.h)) ----
    {
      const float4* x4 = hnew4 + hf * 8;
      float s = dot4(pw0, x4[0]) + dot4(pw1, x4[1]) + dot4(pw2, x4[2]) + dot4(pw3, x4[3])
              + dot4(pw4, x4[4]) + dot4(pw5, x4[5]) + dot4(pw6, x4[6]) + dot4(pw7, x4[7]);
      s += __shfl_xor(s, 1, 64);
      if (hf == 0) {
        float v = fmaxf(s + b2, 0.f);
        if (o < 128) abuf[o] = v; else cbuf[o - 128] = v;
      }
    }
    __syncthreads();

    // ---- P3: gate, pm, z_lin, combine ----
    {
      float sg = dot4(q0, abuf4[c * 4 + 0]) + dot4(q1, abuf4[c * 4 + 1])
               + dot4(q2, abuf4[c * 4 + 2]) + dot4(q3, abuf4[c * 4 + 3]);
      float sp = 0.f;
#pragma unroll
      for (int k = 0; k < 4; ++k)
        sp += dot4(phz4[jh * 256 + k * 64 + lane], cbuf4[c * 4 + k]);
      float zl = 0.f;
      if (c < 4) {
#pragma unroll
        for (int k = 0; k < 4; ++k)
          zl += dot4(zl4[jh * 128 + k * 32 + (j & 7) * 4 + c], hnew4[c * 4 + k]);
      }
      sg += __shfl_xor(sg, 1, 64); sg += __shfl_xor(sg, 2, 64); sg += __shfl_xor(sg, 4, 64);
      sp += __shfl_xor(sp, 1, 64); sp += __shfl_xor(sp, 2, 64); sp += __shfl_xor(sp, 4, 64);
      zl += __shfl_xor(zl, 1, 64); zl += __shfl_xor(zl, 2, 64);
      if (c == 0) {
        float g = sigf(sg + bg);
        float z = (1.f - g) * (zl + bz) + g * (sp + bp);
        zbuf[j] = z;
        zout[(size_t)t * 64 + j] = z;   // z-sequence for obs kernel
      }
    }
    __syncthreads();
  }
}

// Observation head: fully parallel over t. Block t (64 threads) reads z_t,
// computes relu(olx.relu(olh.z)) and relu(osx.relu(osh.z)) -> out[0,t,:].
__global__ __launch_bounds__(64) void obs_kernel(
    const float* __restrict__ zseq,
    const float* __restrict__ W_olh, const float* __restrict__ b_olh,
    const float* __restrict__ W_olx, const float* __restrict__ b_olx,
    const float* __restrict__ W_osh, const float* __restrict__ b_osh,
    const float* __restrict__ W_osx, const float* __restrict__ b_osx,
    float* __restrict__ out) {
  const int t = blockIdx.x;
  const int r = threadIdx.x;
  __shared__ __align__(16) float zt[64], ol[64], os[64];
  zt[r] = zseq[(size_t)t * 64 + r];
  __syncthreads();
  float a1 = b_olh[r], a2 = b_osh[r];
#pragma unroll
  for (int k = 0; k < 16; ++k) {
    float4 v = ((const float4*)zt)[k];
    a1 = fmaf(ld4(W_olh + r * 64 + k * 4).x, v.x,
         fmaf(ld4(W_olh + r * 64 + k * 4).y, v.y,
         fmaf(ld4(W_olh + r * 64 + k * 4).z, v.z,
         fmaf(ld4(W_olh + r * 64 + k * 4).w, v.w, a1))));
    a2 = fmaf(ld4(W_osh + r * 64 + k * 4).x, v.x,
         fmaf(ld4(W_osh + r * 64 + k * 4).y, v.y,
         fmaf(ld4(W_osh + r * 64 + k * 4).z, v.z,
         fmaf(ld4(W_osh + r * 64 + k * 4).w, v.w, a2))));
  }
  ol[r] = fmaxf(a1, 0.f);
  os[r] = fmaxf(a2, 0.f);
  __syncthreads();
  const bool loc = (r < 32);
  const float* Wx = loc ? (W_olx + r * 64) : (W_osx + (r - 32) * 64);
  const float* xb = loc ? ol : os;
  float acc = loc ? b_olx[r] : b_osx[r - 32];
#pragma unroll
  for (int k = 0; k < 16; ++k) {
    float4 w = ld4(Wx + k * 4);
    float4 v = ((const float4*)xb)[k];
    acc = fmaf(w.x, v.x, fmaf(w.y, v.y, fmaf(w.z, v.z, fmaf(w.w, v.w, acc))));
  }
  out[(size_t)t * 64 + r] = fmaxf(acc, 0.f);
}

// out[n] = out[n mod 16384] for n >= 16384 (16384 = T*2X, power of two).
__global__ __launch_bounds__(256) void bcast_kernel(float* __restrict__ out) {
  const size_t total4 = (size_t)Bc * Tc * (2 * Xc) / 4;
  const size_t src4   = (size_t)Tc * (2 * Xc) / 4;
  const float4* s = (const float4*)out;
  float4* o = (float4*)out;
  size_t stride = (size_t)gridDim.x * blockDim.x;
  for (size_t i = (size_t)blockIdx.x * blockDim.x + threadIdx.x + src4;
       i < total4; i += stride) {
    o[i] = s[i & (src4 - 1)];
  }
}

extern "C" void kernel_launch(void* const* d_in, const int* in_sizes, int n_in,
                              void* d_out, int out_size, void* d_ws, size_t ws_size,
                              hipStream_t stream) {
  (void)in_sizes; (void)n_in; (void)d_ws; (void)ws_size; (void)out_size;
  const float* z0     = (const float*)d_in[1];
  const float* h0     = (const float*)d_in[2];
  const float* W_ih   = (const float*)d_in[3];
  const float* W_hh   = (const float*)d_in[4];
  const float* b_ih   = (const float*)d_in[5];
  const float* b_hh   = (const float*)d_in[6];
  const float* W_gzh  = (const float*)d_in[7];
  const float* b_gzh  = (const float*)d_in[8];
  const float* W_ghz  = (const float*)d_in[9];
  const float* b_ghz  = (const float*)d_in[10];
  const float* W_pzh  = (const float*)d_in[11];
  const float* b_pzh  = (const float*)d_in[12];
  const float* W_phz  = (const float*)d_in[13];
  const float* b_phz  = (const float*)d_in[14];
  const float* W_zloc = (const float*)d_in[15];
  const float* b_zloc = (const float*)d_in[16];
  const float* W_olh  = (const float*)d_in[19];
  const float* b_olh  = (const float*)d_in[20];
  const float* W_olx  = (const float*)d_in[21];
  const float* b_olx  = (const float*)d_in[22];
  const float* W_osh  = (const float*)d_in[23];
  const float* b_osh  = (const float*)d_in[24];
  const float* W_osx  = (const float*)d_in[25];
  const float* b_osx  = (const float*)d_in[26];
  float* out = (float*)d_out;

  // z-sequence scratch lives in out[b=1] region (overwritten later by bcast).
  float* zseq = out + (size_t)Tc * 2 * Xc;

  chain_kernel<<<1, 512, 0, stream>>>(
      z0, h0, W_ih, W_hh, b_ih, b_hh,
      W_gzh, b_gzh, W_ghz, b_ghz, W_pzh, b_pzh, W_phz, b_phz,
      W_zloc, b_zloc, zseq);

  obs_kernel<<<Tc, 64, 0, stream>>>(
      zseq, W_olh, b_olh, W_olx, b_olx, W_osh, b_osh, W_osx, b_osx, out);

  bcast_kernel<<<2048, 256, 0, stream>>>(out);
}

// Round 8
// 386.003 us; speedup vs baseline: 3.2792x; 1.1384x over previous
//
#include <hip/hip_runtime.h>
#include <math.h>

static constexpr int Zc  = 64;
static constexpr int Xc  = 32;
static constexpr int Bc  = 4096;
static constexpr int Tc  = 256;

__device__ __forceinline__ float sigf(float x) {
  float e = __expf(-x);
  return __builtin_amdgcn_rcpf(1.0f + e);
}
__device__ __forceinline__ float tanh_fast(float x) {
  float xc = fminf(fmaxf(x, -15.0f), 15.0f);
  float e  = __expf(-2.0f * xc);
  return (1.0f - e) * __builtin_amdgcn_rcpf(1.0f + e);
}
__device__ __forceinline__ float dot4(float4 w, float4 v) {
  return fmaf(w.x, v.x, fmaf(w.y, v.y, fmaf(w.z, v.z, w.w * v.w)));
}
__device__ __forceinline__ float4 ld4(const float* p) { return *(const float4*)p; }

// DPP lane moves (VALU-rate, replaces ds_swizzle-based __shfl_xor).
// 0xB1 = quad_perm(1,0,3,2) -> xor1 ; 0x4E = quad_perm(2,3,0,1) -> xor2 ;
// 0x141 = row_half_mirror: within each 8-lane half-row, lane i <-> 7-i
// (direction-unambiguous cross-quad exchange for the 8-group sum).
template <int CTRL>
__device__ __forceinline__ float dppmov(float x) {
  return __int_as_float(
      __builtin_amdgcn_update_dpp(0, __float_as_int(x), CTRL, 0xF, 0xF, true));
}
__device__ __forceinline__ float red8(float x) {   // full sum over 8-lane group
  x += dppmov<0xB1>(x);
  x += dppmov<0x4E>(x);
  x += dppmov<0x141>(x);
  return x;
}

// LDS-only barrier: waits DS ops, NOT vmem (global z-store stays in flight).
__device__ __forceinline__ void bar_lds() {
  asm volatile("s_waitcnt lgkmcnt(0)" ::: "memory");
  __builtin_amdgcn_s_barrier();
  asm volatile("" ::: "memory");
}

// Serial recurrence, 1 block x 512 threads (8 waves), 3 lgkm-barriers/step.
// Per-thread register state = 24 named float4 (96 floats), same as R6.
__global__ __launch_bounds__(512) void chain_kernel(
    const float* __restrict__ z0, const float* __restrict__ h0,
    const float* __restrict__ W_ih, const float* __restrict__ W_hh,
    const float* __restrict__ b_ih, const float* __restrict__ b_hh,
    const float* __restrict__ W_gzh, const float* __restrict__ b_gzh,
    const float* __restrict__ W_ghz, const float* __restrict__ b_ghz,
    const float* __restrict__ W_pzh, const float* __restrict__ b_pzh,
    const float* __restrict__ W_phz, const float* __restrict__ b_phz,
    const float* __restrict__ W_zloc, const float* __restrict__ b_zloc,
    float* __restrict__ zout) {
  const int tid  = threadIdx.x;
  const int lane = tid & 63;
  const int j    = tid >> 3;        // 0..63  (P1 + P3 output index)
  const int c    = tid & 7;         // 0..7   (K-chunk / eighth index)
  const int o    = tid >> 1;        // 0..255 (P2 output index)
  const int hf   = tid & 1;         // P2 K-half
  const int jh   = tid >> 6;        // wave index

  __shared__ __align__(16) float zbuf[64];
  __shared__ __align__(16) float hA[64];
  __shared__ __align__(16) float hB[64];
  __shared__ __align__(16) float abuf[128];
  __shared__ __align__(16) float cbuf[128];
  __shared__ __align__(16) float lds_phz[8192];  // [jh][k][lane] f4-interleaved
  __shared__ __align__(16) float lds_zl [4096];  // [jh][k][jl*4+c] f4-interleaved

  float4* zbuf4 = (float4*)zbuf;
  float4* abuf4 = (float4*)abuf;
  float4* cbuf4 = (float4*)cbuf;
  float4* phz4  = (float4*)lds_phz;
  float4* zl4   = (float4*)lds_zl;

  // ---------------- staging (identical to R6) ----------------
  const float* Wsrc = (c < 4) ? W_ih : W_hh;
  const int cc = (c & 3) * 16;
  float4 g0  = ld4(Wsrc + (j)       * 64 + cc +  0);
  float4 g1  = ld4(Wsrc + (j)       * 64 + cc +  4);
  float4 g2  = ld4(Wsrc + (j)       * 64 + cc +  8);
  float4 g3  = ld4(Wsrc + (j)       * 64 + cc + 12);
  float4 g4  = ld4(Wsrc + (64 + j)  * 64 + cc +  0);
  float4 g5  = ld4(Wsrc + (64 + j)  * 64 + cc +  4);
  float4 g6  = ld4(Wsrc + (64 + j)  * 64 + cc +  8);
  float4 g7  = ld4(Wsrc + (64 + j)  * 64 + cc + 12);
  float4 g8  = ld4(Wsrc + (128 + j) * 64 + cc +  0);
  float4 g9  = ld4(Wsrc + (128 + j) * 64 + cc +  4);
  float4 g10 = ld4(Wsrc + (128 + j) * 64 + cc +  8);
  float4 g11 = ld4(Wsrc + (128 + j) * 64 + cc + 12);
  const float br  = b_ih[j] + b_hh[j];
  const float bu  = b_ih[64 + j] + b_hh[64 + j];
  const float bin = b_ih[128 + j];
  const float bhn = b_hh[128 + j];

  const float* Wp2 = (o < 128) ? (W_gzh + o * 64) : (W_pzh + (o - 128) * 64);
  const float* Wp2h = Wp2 + hf * 32;
  float4 pw0 = ld4(Wp2h +  0), pw1 = ld4(Wp2h +  4);
  float4 pw2 = ld4(Wp2h +  8), pw3 = ld4(Wp2h + 12);
  float4 pw4 = ld4(Wp2h + 16), pw5 = ld4(Wp2h + 20);
  float4 pw6 = ld4(Wp2h + 24), pw7 = ld4(Wp2h + 28);
  const float b2 = (o < 128) ? b_gzh[o] : b_pzh[o - 128];

  const float* Wq = W_ghz + j * 128 + c * 16;
  float4 q0 = ld4(Wq + 0), q1 = ld4(Wq + 4), q2 = ld4(Wq + 8), q3 = ld4(Wq + 12);
  const float bg = b_ghz[j];
  const float bp = b_phz[j];
  const float bz = b_zloc[j];

#pragma unroll
  for (int k = 0; k < 4; ++k)
    phz4[jh * 256 + k * 64 + lane] = ld4(W_phz + j * 128 + c * 16 + k * 4);
  if (c < 4) {
#pragma unroll
    for (int k = 0; k < 4; ++k)
      zl4[jh * 128 + k * 32 + (j & 7) * 4 + c] = ld4(W_zloc + j * 64 + c * 16 + k * 4);
  }

  if (tid < 64) { zbuf[tid] = z0[tid]; hA[tid] = h0[tid]; }
  __syncthreads();

  for (int t = 0; t < Tc; ++t) {
    float* hold = (t & 1) ? hB : hA;
    float* hnew = (t & 1) ? hA : hB;
    float4* hold4 = (float4*)hold;
    float4* hnew4 = (float4*)hnew;

    // ---- P1: GRU ----
    {
      const float4* x4 = ((c < 4) ? zbuf4 : hold4) + (c & 3) * 4;
      float pr = dot4(g0, x4[0]) + dot4(g1, x4[1]) + dot4(g2, x4[2]) + dot4(g3, x4[3]);
      float pu = dot4(g4, x4[0]) + dot4(g5, x4[1]) + dot4(g6, x4[2]) + dot4(g7, x4[3]);
      float pn = dot4(g8, x4[0]) + dot4(g9, x4[1]) + dot4(g10, x4[2]) + dot4(g11, x4[3]);
      pr = red8(pr);
      pu = red8(pu);
      pn += dppmov<0xB1>(pn);
      pn += dppmov<0x4E>(pn);            // quad sums (i-side / h-side)
      float pno = dppmov<0x141>(pn);     // opposite quad's sum
      float i_n = ((c < 4) ? pn : pno) + bin;
      float h_n = ((c < 4) ? pno : pn) + bhn;
      float r  = sigf(pr + br);
      float u  = sigf(pu + bu);
      float nn = tanh_fast(i_n + r * h_n);
      float hv = (1.f - u) * nn + u * hold[j];
      if (c == 0) hnew[j] = hv;
    }
    bar_lds();

    // ---- P2: trans hiddens (relu(gzh.h), relu(pzh.h)) ----
    {
      const float4* x4 = hnew4 + hf * 8;
      float s = dot4(pw0, x4[0]) + dot4(pw1, x4[1]) + dot4(pw2, x4[2]) + dot4(pw3, x4[3])
              + dot4(pw4, x4[4]) + dot4(pw5, x4[5]) + dot4(pw6, x4[6]) + dot4(pw7, x4[7]);
      s += dppmov<0xB1>(s);              // xor1: both lanes of pair get sum
      if (hf == 0) {
        float v = fmaxf(s + b2, 0.f);
        if (o < 128) abuf[o] = v; else cbuf[o - 128] = v;
      }
    }
    bar_lds();

    // ---- P3: gate, pm, z_lin, combine ----
    {
      float sg = dot4(q0, abuf4[c * 4 + 0]) + dot4(q1, abuf4[c * 4 + 1])
               + dot4(q2, abuf4[c * 4 + 2]) + dot4(q3, abuf4[c * 4 + 3]);
      float sp = 0.f;
#pragma unroll
      for (int k = 0; k < 4; ++k)
        sp += dot4(phz4[jh * 256 + k * 64 + lane], cbuf4[c * 4 + k]);
      float zl = 0.f;
      if (c < 4) {
#pragma unroll
        for (int k = 0; k < 4; ++k)
          zl += dot4(zl4[jh * 128 + k * 32 + (j & 7) * 4 + c], hnew4[c * 4 + k]);
      }
      sg = red8(sg);
      sp = red8(sp);
      zl += dppmov<0xB1>(zl);
      zl += dppmov<0x4E>(zl);            // c==0 holds sum over c=0..3
      if (c == 0) {
        float g = sigf(sg + bg);
        float z = (1.f - g) * (zl + bz) + g * (sp + bp);
        zbuf[j] = z;
        zout[(size_t)t * 64 + j] = z;    // fire-and-forget (vmcnt never drained)
      }
    }
    bar_lds();
  }
}

// Observation head: fully parallel over t. Block t (64 threads) reads z_t,
// computes relu(olx.relu(olh.z)) and relu(osx.relu(osh.z)) -> out[0,t,:].
__global__ __launch_bounds__(64) void obs_kernel(
    const float* __restrict__ zseq,
    const float* __restrict__ W_olh, const float* __restrict__ b_olh,
    const float* __restrict__ W_olx, const float* __restrict__ b_olx,
    const float* __restrict__ W_osh, const float* __restrict__ b_osh,
    const float* __restrict__ W_osx, const float* __restrict__ b_osx,
    float* __restrict__ out) {
  const int t = blockIdx.x;
  const int r = threadIdx.x;
  __shared__ __align__(16) float zt[64], ol[64], os[64];
  zt[r] = zseq[(size_t)t * 64 + r];
  __syncthreads();
  float a1 = b_olh[r], a2 = b_osh[r];
#pragma unroll
  for (int k = 0; k < 16; ++k) {
    float4 v  = ((const float4*)zt)[k];
    float4 w1 = ld4(W_olh + r * 64 + k * 4);
    float4 w2 = ld4(W_osh + r * 64 + k * 4);
    a1 = fmaf(w1.x, v.x, fmaf(w1.y, v.y, fmaf(w1.z, v.z, fmaf(w1.w, v.w, a1))));
    a2 = fmaf(w2.x, v.x, fmaf(w2.y, v.y, fmaf(w2.z, v.z, fmaf(w2.w, v.w, a2))));
  }
  ol[r] = fmaxf(a1, 0.f);
  os[r] = fmaxf(a2, 0.f);
  __syncthreads();
  const bool loc = (r < 32);
  const float* Wx = loc ? (W_olx + r * 64) : (W_osx + (r - 32) * 64);
  const float* xb = loc ? ol : os;
  float acc = loc ? b_olx[r] : b_osx[r - 32];
#pragma unroll
  for (int k = 0; k < 16; ++k) {
    float4 w = ld4(Wx + k * 4);
    float4 v = ((const float4*)xb)[k];
    acc = fmaf(w.x, v.x, fmaf(w.y, v.y, fmaf(w.z, v.z, fmaf(w.w, v.w, acc))));
  }
  out[(size_t)t * 64 + r] = fmaxf(acc, 0.f);
}

// out[n] = out[n mod 16384] for n >= 16384 (16384 = T*2X, power of two).
__global__ __launch_bounds__(256) void bcast_kernel(float* __restrict__ out) {
  const size_t total4 = (size_t)Bc * Tc * (2 * Xc) / 4;
  const size_t src4   = (size_t)Tc * (2 * Xc) / 4;
  const float4* s = (const float4*)out;
  float4* o = (float4*)out;
  size_t stride = (size_t)gridDim.x * blockDim.x;
  for (size_t i = (size_t)blockIdx.x * blockDim.x + threadIdx.x + src4;
       i < total4; i += stride) {
    o[i] = s[i & (src4 - 1)];
  }
}

extern "C" void kernel_launch(void* const* d_in, const int* in_sizes, int n_in,
                              void* d_out, int out_size, void* d_ws, size_t ws_size,
                              hipStream_t stream) {
  (void)in_sizes; (void)n_in; (void)d_ws; (void)ws_size; (void)out_size;
  const float* z0     = (const float*)d_in[1];
  const float* h0     = (const float*)d_in[2];
  const float* W_ih   = (const float*)d_in[3];
  const float* W_hh   = (const float*)d_in[4];
  const float* b_ih   = (const float*)d_in[5];
  const float* b_hh   = (const float*)d_in[6];
  const float* W_gzh  = (const float*)d_in[7];
  const float* b_gzh  = (const float*)d_in[8];
  const float* W_ghz  = (const float*)d_in[9];
  const float* b_ghz  = (const float*)d_in[10];
  const float* W_pzh  = (const float*)d_in[11];
  const float* b_pzh  = (const float*)d_in[12];
  const float* W_phz  = (const float*)d_in[13];
  const float* b_phz  = (const float*)d_in[14];
  const float* W_zloc = (const float*)d_in[15];
  const float* b_zloc = (const float*)d_in[16];
  const float* W_olh  = (const float*)d_in[19];
  const float* b_olh  = (const float*)d_in[20];
  const float* W_olx  = (const float*)d_in[21];
  const float* b_olx  = (const float*)d_in[22];
  const float* W_osh  = (const float*)d_in[23];
  const float* b_osh  = (const float*)d_in[24];
  const float* W_osx  = (const float*)d_in[25];
  const float* b_osx  = (const float*)d_in[26];
  float* out = (float*)d_out;

  // z-sequence scratch lives in out[b=1] region (overwritten later by bcast).
  float* zseq = out + (size_t)Tc * 2 * Xc;

  chain_kernel<<<1, 512, 0, stream>>>(
      z0, h0, W_ih, W_hh, b_ih, b_hh,
      W_gzh, b_gzh, W_ghz, b_ghz, W_pzh, b_pzh, W_phz, b_phz,
      W_zloc, b_zloc, zseq);

  obs_kernel<<<Tc, 64, 0, stream>>>(
      zseq, W_olh, b_olh, W_olx, b_olx, W_osh, b_osh, W_osx, b_osx, out);

  bcast_kernel<<<2048, 256, 0, stream>>>(out);
}

// Round 9
// 348.552 us; speedup vs baseline: 3.6316x; 1.1074x over previous
//
#include <hip/hip_runtime.h>
#include <math.h>

static constexpr int Zc  = 64;
static constexpr int Xc  = 32;
static constexpr int Bc  = 4096;
static constexpr int Tc  = 256;

__device__ __forceinline__ float sigf(float x) {
  float e = __expf(-x);
  return __builtin_amdgcn_rcpf(1.0f + e);
}
__device__ __forceinline__ float tanh_fast(float x) {
  float xc = fminf(fmaxf(x, -15.0f), 15.0f);
  float e  = __expf(-2.0f * xc);
  return (1.0f - e) * __builtin_amdgcn_rcpf(1.0f + e);
}
__device__ __forceinline__ float dot4(float4 w, float4 v) {
  return fmaf(w.x, v.x, fmaf(w.y, v.y, fmaf(w.z, v.z, w.w * v.w)));
}
__device__ __forceinline__ float4 ld4(const float* p) { return *(const float4*)p; }

// DPP lane moves: 0xB1=xor1(quad_perm 1,0,3,2), 0x4E=xor2(2,3,0,1),
// 0x141=row_half_mirror (lane i <-> 7-i within 8-lane half-rows).
template <int CTRL>
__device__ __forceinline__ float dppmov(float x) {
  return __int_as_float(
      __builtin_amdgcn_update_dpp(0, __float_as_int(x), CTRL, 0xF, 0xF, true));
}
__device__ __forceinline__ float red8(float x) {
  x += dppmov<0xB1>(x);
  x += dppmov<0x4E>(x);
  x += dppmov<0x141>(x);
  return x;
}
__device__ __forceinline__ float red4(float x) {
  x += dppmov<0xB1>(x);
  x += dppmov<0x4E>(x);
  return x;
}

// LDS-only barrier (global z-store stays in flight; vmcnt never drained in-loop)
__device__ __forceinline__ void bar_lds() {
  asm volatile("s_waitcnt lgkmcnt(0)" ::: "memory");
  __builtin_amdgcn_s_barrier();
  asm volatile("" ::: "memory");
}

// chunk-padded state layout: element k at [k + 4*(k>>4)] -> the 8 possible
// 16-float chunks of a 64-vector start at 20c floats = distinct banks.
#define PADIDX(k) ((k) + 4 * ((k) >> 4))

// 1 block x 512 threads (8 waves), 3 lgkm-barriers/step, DS-inst-minimized:
//  group A (waves 0-3): P1 GRU (2 outputs j0,j1 per thread, chunk c of K=128,
//                       8-lane red) ; P2-phase: zloc GEMV (chunk of K=64, 4-lane red)
//  group B (waves 4-7): P2 gzh/pzh (4 outputs per thread, chunk ch of K=64) ;
//                       P3 gate+pm (2 outputs, chunk c3 of K=128) + z-combine
// All weights in 32 named float4/thread (128 VGPR); h-recurrence value kept in
// writer-lane registers (hp0/hp1) so h_prev is never re-read from LDS.
__global__ __launch_bounds__(512) void chain_kernel(
    const float* __restrict__ z0, const float* __restrict__ h0,
    const float* __restrict__ W_ih, const float* __restrict__ W_hh,
    const float* __restrict__ b_ih, const float* __restrict__ b_hh,
    const float* __restrict__ W_gzh, const float* __restrict__ b_gzh,
    const float* __restrict__ W_ghz, const float* __restrict__ b_ghz,
    const float* __restrict__ W_pzh, const float* __restrict__ b_pzh,
    const float* __restrict__ W_phz, const float* __restrict__ b_phz,
    const float* __restrict__ W_zloc, const float* __restrict__ b_zloc,
    float* __restrict__ zout) {
  const int tid  = threadIdx.x;
  const bool gB  = (tid >= 256);
  const int idx  = tid & 255;

  // LDS: zP[0,80) bank0 | hPA[80,160) bank16 | hPB[176,256) bank16
  //      aP[256,416) | cP[416,576) | zlb[576,640)
  __shared__ __align__(16) float S[640];
  float* zP  = S;
  float* hPA = S + 80;
  float* hPB = S + 176;
  float* aP  = S + 256;
  float* cP  = S + 416;
  float* zlb = S + 576;

  float4 W00{},W01{},W02{},W03{},W04{},W05{},W06{},W07{},
         W08{},W09{},W10{},W11{},W12{},W13{},W14{},W15{},
         W16{},W17{},W18{},W19{},W20{},W21{},W22{},W23{},
         W24{},W25{},W26{},W27{},W28{},W29{},W30{},W31{};
  float b0=0,b1=0,b2=0,b3=0,b4=0,b5=0,b6=0,b7=0,b8=0;
  float hp0=0, hp1=0;

  // role indices
  const int p  = idx >> 3, c  = idx & 7;    // A:P1  B:P3
  const int jz = idx >> 2, cz = idx & 3;    // A:zl
  const int q  = idx >> 2, ch = idx & 3;    // B:P2
  const int j0 = 2 * p, j1 = 2 * p + 1;
  const int o  = 4 * q + ch;                // B's own P2 output
  float* p2dst = nullptr;

  // ---------------- staging ----------------
  if (!gB) {
    const float* Ws = (c < 4) ? W_ih : W_hh;
    const int col = (c & 3) * 16;
    const float* r0p = Ws + (j0)       * 64 + col;
    const float* u0p = Ws + (64 + j0)  * 64 + col;
    const float* n0p = Ws + (128 + j0) * 64 + col;
    const float* r1p = Ws + (j1)       * 64 + col;
    const float* u1p = Ws + (64 + j1)  * 64 + col;
    const float* n1p = Ws + (128 + j1) * 64 + col;
    W00=ld4(r0p); W01=ld4(r0p+4); W02=ld4(r0p+8); W03=ld4(r0p+12);
    W04=ld4(u0p); W05=ld4(u0p+4); W06=ld4(u0p+8); W07=ld4(u0p+12);
    W08=ld4(n0p); W09=ld4(n0p+4); W10=ld4(n0p+8); W11=ld4(n0p+12);
    W12=ld4(r1p); W13=ld4(r1p+4); W14=ld4(r1p+8); W15=ld4(r1p+12);
    W16=ld4(u1p); W17=ld4(u1p+4); W18=ld4(u1p+8); W19=ld4(u1p+12);
    W20=ld4(n1p); W21=ld4(n1p+4); W22=ld4(n1p+8); W23=ld4(n1p+12);
    const float* zp = W_zloc + jz * 64 + cz * 16;
    W24=ld4(zp); W25=ld4(zp+4); W26=ld4(zp+8); W27=ld4(zp+12);
    b0 = b_ih[j0] + b_hh[j0];
    b1 = b_ih[64 + j0] + b_hh[64 + j0];
    b2 = b_ih[128 + j0];
    b3 = b_hh[128 + j0];
    b4 = b_ih[j1] + b_hh[j1];
    b5 = b_ih[64 + j1] + b_hh[64 + j1];
    b6 = b_ih[128 + j1];
    b7 = b_hh[128 + j1];
    b8 = b_zloc[jz];
    hp0 = h0[j0];
    hp1 = h0[j1];
  } else {
    const bool gz = (q < 32);
    const float* M = gz ? W_gzh : W_pzh;
    const int rb = gz ? 4 * q : 4 * q - 128;
    const float* r0p = M + (rb + 0) * 64 + ch * 16;
    const float* r1p = M + (rb + 1) * 64 + ch * 16;
    const float* r2p = M + (rb + 2) * 64 + ch * 16;
    const float* r3p = M + (rb + 3) * 64 + ch * 16;
    W00=ld4(r0p); W01=ld4(r0p+4); W02=ld4(r0p+8); W03=ld4(r0p+12);
    W04=ld4(r1p); W05=ld4(r1p+4); W06=ld4(r1p+8); W07=ld4(r1p+12);
    W08=ld4(r2p); W09=ld4(r2p+4); W10=ld4(r2p+8); W11=ld4(r2p+12);
    W12=ld4(r3p); W13=ld4(r3p+4); W14=ld4(r3p+8); W15=ld4(r3p+12);
    const float* ga = W_ghz + j0 * 128 + c * 16;
    const float* gb = W_ghz + j1 * 128 + c * 16;
    const float* pa = W_phz + j0 * 128 + c * 16;
    const float* pb = W_phz + j1 * 128 + c * 16;
    W16=ld4(ga); W17=ld4(ga+4); W18=ld4(ga+8); W19=ld4(ga+12);
    W20=ld4(gb); W21=ld4(gb+4); W22=ld4(gb+8); W23=ld4(gb+12);
    W24=ld4(pa); W25=ld4(pa+4); W26=ld4(pa+8); W27=ld4(pa+12);
    W28=ld4(pb); W29=ld4(pb+4); W30=ld4(pb+8); W31=ld4(pb+12);
    b0 = gz ? b_gzh[o] : b_pzh[o - 128];
    b1 = b_ghz[j0];
    b2 = b_ghz[j1];
    b3 = b_phz[j0];
    b4 = b_phz[j1];
    p2dst = gz ? (aP + PADIDX(o)) : (cP + PADIDX(o - 128));
  }

  if (tid < 64) {
    zP[PADIDX(tid)]  = z0[tid];
    hPA[PADIDX(tid)] = h0[tid];   // unused values; hp regs hold the recurrence
  }
  __syncthreads();

  for (int t = 0; t < Tc; ++t) {
    float* hold = (t & 1) ? hPB : hPA;
    float* hnew = (t & 1) ? hPA : hPB;

    // ---- P1: GRU (group A) ----
    if (!gB) {
      const float* x = ((c < 4) ? zP : hold) + 20 * (c & 3);
      float4 x0 = ld4(x), x1 = ld4(x + 4), x2 = ld4(x + 8), x3 = ld4(x + 12);
      float pr0 = dot4(W00,x0)+dot4(W01,x1)+dot4(W02,x2)+dot4(W03,x3);
      float pu0 = dot4(W04,x0)+dot4(W05,x1)+dot4(W06,x2)+dot4(W07,x3);
      float pn0 = dot4(W08,x0)+dot4(W09,x1)+dot4(W10,x2)+dot4(W11,x3);
      float pr1 = dot4(W12,x0)+dot4(W13,x1)+dot4(W14,x2)+dot4(W15,x3);
      float pu1 = dot4(W16,x0)+dot4(W17,x1)+dot4(W18,x2)+dot4(W19,x3);
      float pn1 = dot4(W20,x0)+dot4(W21,x1)+dot4(W22,x2)+dot4(W23,x3);
      pr0 = red8(pr0); pu0 = red8(pu0);
      pr1 = red8(pr1); pu1 = red8(pu1);
      pn0 += dppmov<0xB1>(pn0); pn0 += dppmov<0x4E>(pn0);
      float pno0 = dppmov<0x141>(pn0);
      pn1 += dppmov<0xB1>(pn1); pn1 += dppmov<0x4E>(pn1);
      float pno1 = dppmov<0x141>(pn1);
      const bool zi = (c < 4);
      float in0 = (zi ? pn0 : pno0) + b2, hn0 = (zi ? pno0 : pn0) + b3;
      float in1 = (zi ? pn1 : pno1) + b6, hn1 = (zi ? pno1 : pn1) + b7;
      float r0 = sigf(pr0 + b0), u0 = sigf(pu0 + b1);
      float r1 = sigf(pr1 + b4), u1 = sigf(pu1 + b5);
      float nn0 = tanh_fast(in0 + r0 * hn0);
      float nn1 = tanh_fast(in1 + r1 * hn1);
      float hv0 = (1.f - u0) * nn0 + u0 * hp0;   // valid in lane c==0 (its hp0 chain)
      float hv1 = (1.f - u1) * nn1 + u1 * hp1;   // valid in lane c==1
      hp0 = hv0; hp1 = hv1;
      if (c < 2) {
        int js = (c == 0) ? j0 : j1;
        hnew[PADIDX(js)] = (c == 0) ? hv0 : hv1;
      }
    }
    bar_lds();

    // ---- P2: gzh/pzh hiddens (group B) || zloc GEMV (group A) ----
    if (gB) {
      const float* x = hnew + 20 * ch;
      float4 x0 = ld4(x), x1 = ld4(x + 4), x2 = ld4(x + 8), x3 = ld4(x + 12);
      float s0 = dot4(W00,x0)+dot4(W01,x1)+dot4(W02,x2)+dot4(W03,x3);
      float s1 = dot4(W04,x0)+dot4(W05,x1)+dot4(W06,x2)+dot4(W07,x3);
      float s2 = dot4(W08,x0)+dot4(W09,x1)+dot4(W10,x2)+dot4(W11,x3);
      float s3 = dot4(W12,x0)+dot4(W13,x1)+dot4(W14,x2)+dot4(W15,x3);
      s0 = red4(s0); s1 = red4(s1); s2 = red4(s2); s3 = red4(s3);
      float own = (ch == 0) ? s0 : (ch == 1) ? s1 : (ch == 2) ? s2 : s3;
      *p2dst = fmaxf(own + b0, 0.f);
    } else {
      const float* x = hnew + 20 * cz;
      float4 x0 = ld4(x), x1 = ld4(x + 4), x2 = ld4(x + 8), x3 = ld4(x + 12);
      float zv = dot4(W24,x0)+dot4(W25,x1)+dot4(W26,x2)+dot4(W27,x3);
      zv = red4(zv);
      if (cz == 0) zlb[jz] = zv + b8;
    }
    bar_lds();

    // ---- P3: gate + pm + z combine (group B) ----
    if (gB) {
      const float* xa = aP + 20 * c;
      const float* xc = cP + 20 * c;
      float4 a0 = ld4(xa), a1 = ld4(xa + 4), a2 = ld4(xa + 8), a3 = ld4(xa + 12);
      float4 c0 = ld4(xc), c1 = ld4(xc + 4), c2 = ld4(xc + 8), c3v = ld4(xc + 12);
      float sg0 = dot4(W16,a0)+dot4(W17,a1)+dot4(W18,a2)+dot4(W19,a3);
      float sg1 = dot4(W20,a0)+dot4(W21,a1)+dot4(W22,a2)+dot4(W23,a3);
      float sp0 = dot4(W24,c0)+dot4(W25,c1)+dot4(W26,c2)+dot4(W27,c3v);
      float sp1 = dot4(W28,c0)+dot4(W29,c1)+dot4(W30,c2)+dot4(W31,c3v);
      sg0 = red8(sg0); sg1 = red8(sg1);
      sp0 = red8(sp0); sp1 = red8(sp1);
      const bool sel1 = (c == 1);
      int js = sel1 ? j1 : j0;
      float zlv = zlb[js];
      float g  = sigf((sel1 ? sg1 : sg0) + (sel1 ? b2 : b1));
      float pm = (sel1 ? sp1 : sp0) + (sel1 ? b4 : b3);
      float z  = (1.f - g) * zlv + g * pm;
      if (c < 2) {
        zP[PADIDX(js)] = z;
        zout[(size_t)t * 64 + js] = z;   // fire-and-forget
      }
    }
    bar_lds();
  }
}

// Observation head: fully parallel over t (one 64-thread block per t).
__global__ __launch_bounds__(64) void obs_kernel(
    const float* __restrict__ zseq,
    const float* __restrict__ W_olh, const float* __restrict__ b_olh,
    const float* __restrict__ W_olx, const float* __restrict__ b_olx,
    const float* __restrict__ W_osh, const float* __restrict__ b_osh,
    const float* __restrict__ W_osx, const float* __restrict__ b_osx,
    float* __restrict__ out) {
  const int t = blockIdx.x;
  const int r = threadIdx.x;
  __shared__ __align__(16) float zt[64], ol[64], os[64];
  zt[r] = zseq[(size_t)t * 64 + r];
  __syncthreads();
  float a1 = b_olh[r], a2 = b_osh[r];
#pragma unroll
  for (int k = 0; k < 16; ++k) {
    float4 v  = ((const float4*)zt)[k];
    float4 w1 = ld4(W_olh + r * 64 + k * 4);
    float4 w2 = ld4(W_osh + r * 64 + k * 4);
    a1 = fmaf(w1.x, v.x, fmaf(w1.y, v.y, fmaf(w1.z, v.z, fmaf(w1.w, v.w, a1))));
    a2 = fmaf(w2.x, v.x, fmaf(w2.y, v.y, fmaf(w2.z, v.z, fmaf(w2.w, v.w, a2))));
  }
  ol[r] = fmaxf(a1, 0.f);
  os[r] = fmaxf(a2, 0.f);
  __syncthreads();
  const bool loc = (r < 32);
  const float* Wx = loc ? (W_olx + r * 64) : (W_osx + (r - 32) * 64);
  const float* xb = loc ? ol : os;
  float acc = loc ? b_olx[r] : b_osx[r - 32];
#pragma unroll
  for (int k = 0; k < 16; ++k) {
    float4 w = ld4(Wx + k * 4);
    float4 v = ((const float4*)xb)[k];
    acc = fmaf(w.x, v.x, fmaf(w.y, v.y, fmaf(w.z, v.z, fmaf(w.w, v.w, acc))));
  }
  out[(size_t)t * 64 + r] = fmaxf(acc, 0.f);
}

// out[n] = out[n mod 16384] for n >= 16384 (16384 = T*2X, power of two).
__global__ __launch_bounds__(256) void bcast_kernel(float* __restrict__ out) {
  const size_t total4 = (size_t)Bc * Tc * (2 * Xc) / 4;
  const size_t src4   = (size_t)Tc * (2 * Xc) / 4;
  const float4* s = (const float4*)out;
  float4* o = (float4*)out;
  size_t stride = (size_t)gridDim.x * blockDim.x;
  for (size_t i = (size_t)blockIdx.x * blockDim.x + threadIdx.x + src4;
       i < total4; i += stride) {
    o[i] = s[i & (src4 - 1)];
  }
}

extern "C" void kernel_launch(void* const* d_in, const int* in_sizes, int n_in,
                              void* d_out, int out_size, void* d_ws, size_t ws_size,
                              hipStream_t stream) {
  (void)in_sizes; (void)n_in; (void)d_ws; (void)ws_size; (void)out_size;
  const float* z0     = (const float*)d_in[1];
  const float* h0     = (const float*)d_in[2];
  const float* W_ih   = (const float*)d_in[3];
  const float* W_hh   = (const float*)d_in[4];
  const float* b_ih   = (const float*)d_in[5];
  const float* b_hh   = (const float*)d_in[6];
  const float* W_gzh  = (const float*)d_in[7];
  const float* b_gzh  = (const float*)d_in[8];
  const float* W_ghz  = (const float*)d_in[9];
  const float* b_ghz  = (const float*)d_in[10];
  const float* W_pzh  = (const float*)d_in[11];
  const float* b_pzh  = (const float*)d_in[12];
  const float* W_phz  = (const float*)d_in[13];
  const float* b_phz  = (const float*)d_in[14];
  const float* W_zloc = (const float*)d_in[15];
  const float* b_zloc = (const float*)d_in[16];
  const float* W_olh  = (const float*)d_in[19];
  const float* b_olh  = (const float*)d_in[20];
  const float* W_olx  = (const float*)d_in[21];
  const float* b_olx  = (const float*)d_in[22];
  const float* W_osh  = (const float*)d_in[23];
  const float* b_osh  = (const float*)d_in[24];
  const float* W_osx  = (const float*)d_in[25];
  const float* b_osx  = (const float*)d_in[26];
  float* out = (float*)d_out;

  // z-sequence scratch lives in out[b=1] region (overwritten later by bcast).
  float* zseq = out + (size_t)Tc * 2 * Xc;

  chain_kernel<<<1, 512, 0, stream>>>(
      z0, h0, W_ih, W_hh, b_ih, b_hh,
      W_gzh, b_gzh, W_ghz, b_ghz, W_pzh, b_pzh, W_phz, b_phz,
      W_zloc, b_zloc, zseq);

  obs_kernel<<<Tc, 64, 0, stream>>>(
      zseq, W_olh, b_olh, W_olx, b_olx, W_osh, b_osh, W_osx, b_osx, out);

  bcast_kernel<<<2048, 256, 0, stream>>>(out);
}